// Round 1
// baseline (7083.203 us; speedup 1.0000x reference)
//
#include <hip/hip_runtime.h>
#include <cstdint>

typedef _Float16 f16;
typedef f16  f16x8 __attribute__((ext_vector_type(8)));
typedef float f32x4 __attribute__((ext_vector_type(4)));

#define NB   32      // batch
#define TT   1024    // timesteps
#define DD   512     // input dim
#define HH   512     // hidden dim
#define NWG  64      // persistent workgroups

__device__ __forceinline__ float fsig(float x) {
    return __builtin_amdgcn_rcpf(1.0f + __expf(-x));
}
__device__ __forceinline__ float ftanh(float x) {
    // (e^2x-1)/(e^2x+1) written inf-safe: x->+inf => 1, x->-inf => -1
    return 1.0f - 2.0f * __builtin_amdgcn_rcpf(__expf(2.0f * x) + 1.0f);
}

// ---- setup kernels -------------------------------------------------------

__global__ void k_cast_x(const float* __restrict__ x, f16* __restrict__ x16) {
    int i = (blockIdx.x * 256 + threadIdx.x) * 8;
    float4 a = *(const float4*)(x + i);
    float4 c = *(const float4*)(x + i + 4);
    f16x8 v;
    v[0] = (f16)a.x; v[1] = (f16)a.y; v[2] = (f16)a.z; v[3] = (f16)a.w;
    v[4] = (f16)c.x; v[5] = (f16)c.y; v[6] = (f16)c.z; v[7] = (f16)c.w;
    *(f16x8*)(x16 + i) = v;
}

// W (512 x 2048, row-major, k fast over rows) -> Wp[colp][k] f16, where
// colp = wg*32 + j*4 + gate maps to col2048 = gate*512 + wg*8 + j.
__global__ void k_perm_w(const float* __restrict__ W, f16* __restrict__ Wp) {
    int tid = blockIdx.x * 256 + threadIdx.x;   // 2048*512 total
    int colp = tid >> 9, k = tid & 511;
    int wg = colp >> 5, c = colp & 31;
    int gate = c & 3, j = c >> 2;
    int col = gate * 512 + wg * 8 + j;
    Wp[tid] = (f16)W[k * 2048 + col];
}

__global__ void k_h0(const float* __restrict__ h0, f16* __restrict__ hb) {
    int i = blockIdx.x * 256 + threadIdx.x;     // 32*512
    hb[i] = (f16)h0[i];
}

// ---- persistent LSTM kernel ---------------------------------------------
// Grid = 64 WGs x 256 threads. WG wg owns h-cols [wg*8, wg*8+8).
// Wave w: mt = w>>1 (n-rows mt*16..+16), nt = w&1 (h-cols wg*8+nt*4..+4,
// all 4 gates interleaved as local col c = j*4+gate).

__global__ void __launch_bounds__(256, 1) k_lstm(
    const f16* __restrict__ x16, const f16* __restrict__ Wxp,
    const f16* __restrict__ Whp, const float* __restrict__ b,
    f16* hbuf, uint32_t* flags, float* __restrict__ out)
{
    const int wg  = blockIdx.x;
    const int tid = threadIdx.x;
    const int w   = tid >> 6;
    const int l   = tid & 63;
    const int mt  = w >> 1, nt = w & 1;
    const int lq  = l >> 4, lc = l & 15;

    const int colp = wg * 32 + nt * 16 + lc;   // permuted output column
    const int gate = lc & 3, j_in = lc >> 2;
    const int hcol = wg * 8 + nt * 4 + j_in;   // h-column of this lane's col
    const float bv = b[gate * 512 + hcol];

    const int arow   = mt * 16 + lc;           // n-row this lane loads (A frag)
    const int rm     = l & 3;                  // acc index this lane stores (== gate)
    const int n_mine = mt * 16 + lq * 4 + rm;  // n-row this lane stores

    // Wh fragments resident in VGPRs for the whole run (critical path).
    f16x8 Bh[16];
    {
        const f16* p = Whp + colp * 512 + lq * 8;
        #pragma unroll
        for (int ks = 0; ks < 16; ++ks) Bh[ks] = *(const f16x8*)(p + ks * 32);
    }
    const f16* wxp  = Wxp + colp * 512 + lq * 8;       // reloaded per step (L1/L2-hot)
    const f16* xrow = x16 + arow * (TT * DD) + lq * 8;

    float c_reg[4] = {0.f, 0.f, 0.f, 0.f};

    for (int t = 0; t < TT; ++t) {
        // ---- x_t @ Wx + b : independent of h, overlaps the barrier wait
        f32x4 acc = {bv, bv, bv, bv};
        {
            const f16* xp = xrow + t * DD;
            #pragma unroll
            for (int ks = 0; ks < 16; ++ks) {
                f16x8 ax = *(const f16x8*)(xp + ks * 32);
                f16x8 bx = *(const f16x8*)(wxp + ks * 32);
                acc = __builtin_amdgcn_mfma_f32_16x16x32_f16(ax, bx, acc, 0, 0, 0);
            }
        }
        // ---- wait until every WG published h_{t-1} (flags[j] >= t)
        if (w == 0) {
            int guard = 0;
            while (true) {
                uint32_t f = __hip_atomic_load(&flags[l], __ATOMIC_RELAXED,
                                               __HIP_MEMORY_SCOPE_SYSTEM);
                if (__all(f >= (uint32_t)t) || ++guard > (1 << 20)) break;
                __builtin_amdgcn_s_sleep(1);
            }
        }
        __syncthreads();
        // ---- h_{t-1} @ Wh : system-coherent loads (bypass stale L1/L2)
        {
            const f16* hb = hbuf + ((t + 1) & 1) * (NB * HH) + arow * HH + lq * 8;
            f16x8 Ah[16];
            #pragma unroll
            for (int ks = 0; ks < 16; ++ks) {
                const f16* p = hb + ks * 32;
                asm volatile("global_load_dwordx4 %0, %1, off sc0 sc1"
                             : "=v"(Ah[ks]) : "v"(p));
            }
            asm volatile("s_waitcnt vmcnt(0)" ::: "memory");
            __builtin_amdgcn_sched_barrier(0);
            #pragma unroll
            for (int ks = 0; ks < 16; ++ks)
                acc = __builtin_amdgcn_mfma_f32_16x16x32_f16(Ah[ks], Bh[ks], acc, 0, 0, 0);
        }
        // ---- gates: each lane-quad holds {i,f,o,g} for one (n-block, hcol)
        float hv = 0.f;
        #pragma unroll
        for (int r = 0; r < 4; ++r) {
            float av = acc[r];
            int base = l & ~3;
            float ai = __shfl(av, base | 0, 64);
            float af = __shfl(av, base | 1, 64);
            float ao = __shfl(av, base | 2, 64);
            float ag = __shfl(av, base | 3, 64);
            float ig = fsig(ai), fg = fsig(af), og = fsig(ao), gg = ftanh(ag);
            float cn = fg * c_reg[r] + ig * gg;   // identical across the quad
            c_reg[r] = cn;
            float h = og * ftanh(cn);
            if (r == rm) hv = h;
        }
        // ---- publish h_t (f16, write-through to IF) + fp32 output
        {
            f16 h16 = (f16)hv;
            uint32_t hvu = (uint32_t)*(unsigned short*)&h16;
            f16* hdst = hbuf + (t & 1) * (NB * HH) + n_mine * HH + hcol;
            asm volatile("global_store_short %0, %1, off sc0 sc1"
                         :: "v"(hdst), "v"(hvu) : "memory");
            out[(n_mine * TT + t) * HH + hcol] = hv;
        }
        asm volatile("s_waitcnt vmcnt(0)" ::: "memory");
        __syncthreads();
        if (tid == 0)
            __hip_atomic_store(&flags[wg], (uint32_t)(t + 1), __ATOMIC_RELAXED,
                               __HIP_MEMORY_SCOPE_SYSTEM);
    }
}

// ---- launch --------------------------------------------------------------

extern "C" void kernel_launch(void* const* d_in, const int* in_sizes, int n_in,
                              void* d_out, int out_size, void* d_ws, size_t ws_size,
                              hipStream_t stream)
{
    (void)in_sizes; (void)n_in; (void)out_size; (void)ws_size;
    const float* x  = (const float*)d_in[0];
    const float* h0 = (const float*)d_in[1];
    const float* Wx = (const float*)d_in[2];
    const float* Wh = (const float*)d_in[3];
    const float* b  = (const float*)d_in[4];
    float* out = (float*)d_out;

    char* ws = (char*)d_ws;
    uint32_t* flags = (uint32_t*)ws;                             // 4 KiB reserved
    f16* x16  = (f16*)(ws + (4 << 10));                          // 32 MiB
    f16* Wxp  = (f16*)(ws + (4 << 10) + (32 << 20));             // 2 MiB
    f16* Whp  = (f16*)(ws + (4 << 10) + (34 << 20));             // 2 MiB
    f16* hbuf = (f16*)(ws + (4 << 10) + (36 << 20));             // 64 KiB (2 bufs)

    hipMemsetAsync(flags, 0, 256, stream);
    k_cast_x<<<8192, 256, 0, stream>>>(x, x16);          // 32*1024*512 / (256*8)
    k_perm_w<<<4096, 256, 0, stream>>>(Wx, Wxp);         // 2048*512 / 256
    k_perm_w<<<4096, 256, 0, stream>>>(Wh, Whp);
    k_h0<<<64, 256, 0, stream>>>(h0, hbuf + NB * HH);    // h_{-1} into buffer 1
    k_lstm<<<NWG, 256, 0, stream>>>(x16, Wxp, Whp, b, hbuf, flags, out);
}